// Round 21
// baseline (564.745 us; speedup 1.0000x reference)
//
#include <hip/hip_runtime.h>
#include <math.h>

// MoEProcessor: B=8, N=4096, D=256, H=W=64, WS=8, NH=8, M=16, E=4, TD=768, HID=1024, TK=2
// Round 21: spectral xm-pairing - each weight load is a 128B-contiguous span covering both
// xms of a pair (DRAM granule 64B->128B, the identified pattern limit). Wl single-xm,
// written from registers in 4 alternating phases; Xl holds both krows. Rest = R20.

#define NB 8
#define NN 4096
#define DD 256

typedef __attribute__((ext_vector_type(8))) short bf16x8;
typedef __attribute__((ext_vector_type(4))) float f32x4;

__device__ __forceinline__ float gelu_f(float v) {
    float u = v * (1.0f + 0.044715f * v * v);
    float e = __expf(-1.5957691f * u);
    return v * __builtin_amdgcn_rcpf(1.0f + e);
}
__device__ __forceinline__ ushort f2bf(float f) {
    uint32_t u = __float_as_uint(f);
    uint32_t r = (u + 0x7fffu + ((u >> 16) & 1u)) >> 16;
    return (ushort)r;
}
__device__ __forceinline__ float b2f(ushort h) {
    return __uint_as_float(((uint32_t)h) << 16);
}

// ---------------- fused x->bf16 + transpose + gate-mean partials ----------------
__global__ void k_cvt_gate_t(const float* __restrict__ src, ushort* __restrict__ xbf,
        ushort* __restrict__ xg, float* __restrict__ gp) {
    __shared__ ushort tile[32][34];
    __shared__ float sred[8][32];
    int nt = blockIdx.x, dt = blockIdx.y, b = blockIdx.z;
    int tx = threadIdx.x, ty = threadIdx.y;
    int n0 = nt * 32, d0 = dt * 32;
    const float* xb = src + ((size_t)b * NN + n0) * DD + d0;
    ushort* xbb = xbf + ((size_t)b * NN + n0) * DD + d0;
    float s = 0.f;
    #pragma unroll
    for (int i = 0; i < 4; ++i) {
        int r = ty + i * 8;
        float v = xb[(size_t)r * DD + tx];
        ushort h = f2bf(v);
        xbb[(size_t)r * DD + tx] = h;
        tile[r][tx] = h;
        s += v;
    }
    sred[ty][tx] = s;
    __syncthreads();
    ushort* xgb = xg + (size_t)b * DD * NN;
    #pragma unroll
    for (int i = 0; i < 4; ++i) {
        int d = d0 + ty + i * 8;
        xgb[(size_t)d * NN + n0 + tx] = tile[tx][ty + i * 8];
    }
    if (ty == 0) {
        float tot = 0.f;
        #pragma unroll
        for (int j = 0; j < 8; ++j) tot += sred[j][tx];
        gp[(((size_t)b * 8 + dt) * 128 + nt) * 32 + tx] = tot;
    }
}

// gate mean-reduce + mlp1, parallel over j-tiles: grid (8 jt, 8 b), block 256.
__global__ void __launch_bounds__(256) k_gate_mm(const float* __restrict__ gp,
        const float* __restrict__ text, const float* __restrict__ w1,
        const float* __restrict__ b1, float* __restrict__ h1) {
    __shared__ float fs[1024];
    __shared__ float sred[8][32];
    int jt = blockIdx.x, b = blockIdx.y;
    int t = threadIdx.x;
    {
        int dt = t >> 5, tx = t & 31;
        const float* base = gp + ((size_t)b * 8 + dt) * 128 * 32 + tx;
        float s = 0.f;
        for (int j = 0; j < 128; j += 4) {
            s += base[(j + 0) * 32] + base[(j + 1) * 32]
               + base[(j + 2) * 32] + base[(j + 3) * 32];
        }
        fs[t] = s * (1.0f / NN);
        for (int j = t; j < 768; j += 256) fs[256 + j] = text[b * 768 + j];
    }
    __syncthreads();
    int jl = t & 31, ks = t >> 5;
    int j = jt * 32 + jl;
    float acc = 0.f;
    int k0 = ks * 128;
    for (int k = k0; k < k0 + 128; ++k) acc += fs[k] * w1[k * 256 + j];
    sred[ks][jl] = acc;
    __syncthreads();
    if (t < 32) {
        float s = b1[jt * 32 + t];
        #pragma unroll
        for (int q = 0; q < 8; ++q) s += sred[q][t];
        h1[b * 256 + jt * 32 + t] = fmaxf(s, 0.f);
    }
}

__global__ void k_gate_top(const float* __restrict__ h1, const float* __restrict__ w2,
                           const float* __restrict__ b2, float* __restrict__ cw,
                           float* __restrict__ wout) {
    __shared__ float lg[8][4];
    int t = threadIdx.x;
    if (t < 32) {
        int b = t >> 2, e = t & 3;
        float acc = b2[e];
        const float* h = h1 + b * 256;
        for (int k = 0; k < 256; ++k) acc += h[k] * w2[k * 4 + e];
        lg[b][e] = acc;
    }
    __syncthreads();
    if (t < 8) {
        int b = t;
        float v[4];
        #pragma unroll
        for (int e = 0; e < 4; ++e) v[e] = lg[b][e];
        int i0 = 0;
        #pragma unroll
        for (int e = 1; e < 4; ++e) if (v[e] > v[i0]) i0 = e;
        int i1 = -1;
        #pragma unroll
        for (int e = 0; e < 4; ++e) {
            if (e == i0) continue;
            if (i1 < 0 || v[e] > v[i1]) i1 = e;
        }
        float v0 = v[i0], v1 = v[i1];
        float e1v = expf(v1 - v0);
        float inv = 1.0f / (1.0f + e1v);
        float w0 = inv, w1v = e1v * inv;
        wout[b * 2 + 0] = w0;
        wout[b * 2 + 1] = w1v;
        float c[4] = {0.f, 0.f, 0.f, 0.f};
        c[i0] += w0; c[i1] += w1v;
        #pragma unroll
        for (int e = 0; e < 4; ++e) cw[b * 4 + e] = c[e];
    }
}

// batched transpose+convert: 9 jobs, grid (256, 1, 9), block (32,8)
__global__ void k_wt_all(const float* s0, const float* s1, const float* s2,
        const float* s3, const float* s4, const float* s5, const float* s6,
        const float* s7, const float* s8,
        ushort* d0, ushort* d1, ushort* d2, ushort* d3, ushort* d4,
        ushort* d5, ushort* d6, ushort* d7, ushort* d8) {
    const float* srcs[9] = {s0, s1, s2, s3, s4, s5, s6, s7, s8};
    ushort* dsts[9] = {d0, d1, d2, d3, d4, d5, d6, d7, d8};
    const int Ks[9] = {256, 1024, 256, 1024, 256, 1024, 256, 256, 256};
    const int Ns[9] = {1024, 256, 1024, 256, 1024, 256, 768, 256, 256};
    __shared__ float tile[32][33];
    int j = blockIdx.z;
    int K = Ks[j], N = Ns[j];
    int tn = N >> 5, tk = K >> 5;
    int tid = blockIdx.x;
    if (tid >= tn * tk) return;
    int n0 = (tid % tn) * 32, k0 = (tid / tn) * 32;
    const float* src = srcs[j];
    ushort* dst = dsts[j];
    int tx = threadIdx.x, ty = threadIdx.y;
    #pragma unroll
    for (int i = 0; i < 4; ++i)
        tile[ty + i * 8][tx] = src[(size_t)(k0 + ty + i * 8) * N + n0 + tx];
    __syncthreads();
    #pragma unroll
    for (int i = 0; i < 4; ++i)
        dst[(size_t)(n0 + ty + i * 8) * K + k0 + tx] = f2bf(tile[tx][ty + i * 8]);
}

// ---------------- MFMA GEMM ----------------
// MODE 0: outb = bf16(gelu(acc+colbias))
// MODE 1: outb = bf16(acc+colbias)
// MODE 5: outb = bf16(acc+rowbias)  (batched)
// MODE 6: outb = bf16(acc+colbias + bf16res)
// MODE 7: outf = combine(acc+colbias, e0p, g1p, g2p, xap, res=xbf, cw)  [final]
template<int MODE>
__global__ void __launch_bounds__(256) k_gemm(const ushort* __restrict__ A,
        const ushort* __restrict__ Bt, const float* __restrict__ bias,
        const void* __restrict__ res, float* __restrict__ outf,
        ushort* __restrict__ outb, const float* __restrict__ cw, int eidx,
        int K, int Ncols, size_t bsA, size_t bsB, size_t bsC,
        const ushort* __restrict__ e0p, const ushort* __restrict__ g1p,
        const ushort* __restrict__ g2p, const ushort* __restrict__ xap) {
    __shared__ alignas(16) char smem[34816];   // staging 32KB; epilogue [128][136] ushort
    ushort* sA = (ushort*)smem;            // [2][4096]
    ushort* sB = (ushort*)(smem + 16384);  // [2][4096]
    int z = blockIdx.z;
    A += z * bsA; Bt += z * bsB;
    if (outf) outf += z * bsC;
    if (outb) outb += z * bsC;
    int m0 = blockIdx.x * 128;
    int n0 = blockIdx.y * 128;
    int t = threadIdx.x;
    int lane = t & 63, wid = t >> 6;
    int wr = wid >> 1, wc = wid & 1;
    int rlo = lane & 15, khi = (lane >> 4) * 8;

    auto stage = [&](int buf, int k0) {
        const ushort* Ab = A + (size_t)m0 * K + k0;
        const ushort* Bb = Bt + (size_t)n0 * K + k0;
        #pragma unroll
        for (int h = 0; h < 2; ++h) {
            int s = t + h * 256;
            int row = s >> 2, kc = (s & 3) * 8;
            __builtin_amdgcn_global_load_lds(
                (const __attribute__((address_space(1))) void*)(Ab + (size_t)row * K + kc),
                (__attribute__((address_space(3))) void*)(sA + buf * 4096 + s * 8),
                16, 0, 0);
            __builtin_amdgcn_global_load_lds(
                (const __attribute__((address_space(1))) void*)(Bb + (size_t)row * K + kc),
                (__attribute__((address_space(3))) void*)(sB + buf * 4096 + s * 8),
                16, 0, 0);
        }
    };

    f32x4 acc[4][4];
    #pragma unroll
    for (int i = 0; i < 4; ++i)
        #pragma unroll
        for (int j = 0; j < 4; ++j) acc[i][j] = (f32x4){0.f, 0.f, 0.f, 0.f};

    int KT = K >> 5;
    stage(0, 0);
    int cur = 0;
    for (int kt = 0; kt < KT; ++kt) {
        __syncthreads();
        if (kt + 1 < KT) stage(cur ^ 1, (kt + 1) << 5);
        const ushort* Ap = sA + cur * 4096;
        const ushort* Bp = sB + cur * 4096;
        bf16x8 af[4], bfr[4];
        #pragma unroll
        for (int i = 0; i < 4; ++i) {
            af[i]  = *(const bf16x8*)(Ap + (wr * 64 + i * 16 + rlo) * 32 + khi);
            bfr[i] = *(const bf16x8*)(Bp + (wc * 64 + i * 16 + rlo) * 32 + khi);
        }
        #pragma unroll
        for (int i = 0; i < 4; ++i)
            #pragma unroll
            for (int j = 0; j < 4; ++j)
                acc[i][j] = __builtin_amdgcn_mfma_f32_16x16x32_bf16(af[i], bfr[j], acc[i][j], 0, 0, 0);
        cur ^= 1;
    }

    float bj4[4];
    if constexpr (MODE != 5) {
        #pragma unroll
        for (int nt = 0; nt < 4; ++nt) bj4[nt] = bias[n0 + wc * 64 + nt * 16 + rlo];
    }

    // single-phase epilogue: [128][136] bf16 arena, 2 barriers total
    ushort* eb = (ushort*)smem;
    __syncthreads();
    #pragma unroll
    for (int mt = 0; mt < 4; ++mt) {
        int row0 = wr * 64 + mt * 16 + (lane >> 4) * 4;
        #pragma unroll
        for (int nt = 0; nt < 4; ++nt) {
            int col = wc * 64 + nt * 16 + rlo;
            #pragma unroll
            for (int j = 0; j < 4; ++j) {
                float v = acc[mt][nt][j];
                if constexpr (MODE == 5)
                    v += bias[m0 + row0 + j];
                else
                    v += bj4[nt];
                if (MODE == 0) v = gelu_f(v);
                eb[(row0 + j) * 136 + col] = f2bf(v);
            }
        }
    }
    __syncthreads();
    const ushort* resb = (const ushort*)res;
    #pragma unroll
    for (int h = 0; h < 8; ++h) {
        int s = t + h * 256;
        int r = s >> 4, c = (s & 15) * 8;
        int grow = m0 + r;
        size_t off = (size_t)grow * Ncols + n0 + c;
        if constexpr (MODE == 6) {
            ushort ee[8], rr[8], oo[8];
            *(uint4*)ee = *(uint4*)&eb[r * 136 + c];
            *(uint4*)rr = *(const uint4*)(resb + off);
            #pragma unroll
            for (int q = 0; q < 8; ++q) oo[q] = f2bf(b2f(ee[q]) + b2f(rr[q]));
            *(uint4*)(outb + off) = *(uint4*)oo;
        } else if constexpr (MODE == 7) {
            int bb = grow >> 12;
            float c0 = cw[bb * 4 + 0], c1 = cw[bb * 4 + 1];
            float c2 = cw[bb * 4 + 2], c3 = cw[bb * 4 + 3];
            float cx = c0 + c1 + c3;
            ushort ee[8], a0[8], a1[8], a2[8], xa[8], xb[8];
            *(uint4*)ee = *(uint4*)&eb[r * 136 + c];
            *(uint4*)a0 = *(const uint4*)(e0p + off);
            *(uint4*)a1 = *(const uint4*)(g1p + off);
            *(uint4*)a2 = *(const uint4*)(g2p + off);
            *(uint4*)xa = *(const uint4*)(xap + off);
            *(uint4*)xb = *(const uint4*)(resb + off);
            float ov[8];
            #pragma unroll
            for (int q = 0; q < 8; ++q)
                ov[q] = c0 * b2f(a0[q]) + c1 * b2f(a1[q]) + c2 * (b2f(a2[q]) + b2f(xa[q]))
                      + c3 * b2f(ee[q]) + cx * b2f(xb[q]);
            *(float4*)(outf + off) = *(float4*)&ov[0];
            *(float4*)(outf + off + 4) = *(float4*)&ov[4];
        } else {
            *(uint4*)(outb + off) = *(uint4*)&eb[r * 136 + c];
        }
    }
}

// ---------------- FNO ----------------
// 256-thread rfft2 on bf16 plane input
__global__ void __launch_bounds__(256) k_rfft2(const ushort* __restrict__ xg, float* __restrict__ xft) {
    __shared__ float plane[64][65];
    __shared__ float s1re[16][66], s1im[16][66];
    __shared__ float twc[64], tws[64];
    int p = blockIdx.x;
    int t = threadIdx.x;
    int tx = t & 63, grp = t >> 6;
    const ushort* src = xg + (size_t)p * 4096;
    #pragma unroll
    for (int i = 0; i < 16; ++i) {
        int row = grp * 16 + i;
        plane[row][tx] = b2f(src[row * 64 + tx]);
    }
    if (t < 64) {
        twc[t] = cosf((float)t * (6.283185307179586f / 64.0f));
        tws[t] = sinf((float)t * (6.283185307179586f / 64.0f));
    }
    __syncthreads();
    int r = tx;
    #pragma unroll
    for (int q = 0; q < 4; ++q) {
        int kw = grp + q * 4;
        float re = 0.f, im = 0.f;
        for (int w = 0; w < 64; ++w) {
            int j = (w * kw) & 63;
            float xv = plane[r][w];
            re += xv * twc[j];
            im -= xv * tws[j];
        }
        s1re[kw][r] = re;
        s1im[kw][r] = im;
    }
    __syncthreads();
    float2* dst = (float2*)xft + (size_t)p * 512;
    #pragma unroll
    for (int q = 0; q < 2; ++q) {
        int oi = t + q * 256;
        int krow = oi >> 4, kw = oi & 15;
        int kh = krow < 16 ? krow : krow + 32;
        float re = 0.f, im = 0.f;
        for (int h = 0; h < 64; ++h) {
            int j = (h * kh) & 63;
            float c = twc[j], s = tws[j];
            float ar = s1re[kw][h], ai = s1im[kw][h];
            re += ar * c + ai * s;
            im += ai * c - ar * s;
        }
        dst[oi] = make_float2(re, im);
    }
}

// ---------------- MFMA spectral (xm-paired: 128B weight granule) ----------------
// grid (16 otile, 8 xm-pair, 4 = region*2 + is), block 512 (8 waves).
// Wl[16 y][16 o][40 i-pad] single-xm (20736 B); Xl[2 krow][16 pack][16 y][40] (40448 B).
__global__ void __launch_bounds__(512) k_spectral(const float* __restrict__ xft,
        const float* __restrict__ w1r, const float* __restrict__ w1i,
        const float* __restrict__ w2r, const float* __restrict__ w2i,
        float* __restrict__ part) {
    __shared__ alignas(16) ushort Wl[16 * 648];       // 20736 B
    __shared__ alignas(16) ushort Xl[2][16 * 632];    // 40448 B (total 61184)
    int rz = blockIdx.z;
    int region = rz >> 1, is = rz & 1;
    const float* wrp = region ? w2r : w1r;
    const float* wip = region ? w2i : w1i;
    int xmp = blockIdx.y;
    int xm0 = xmp * 2;
    int krow0 = region * 16 + xm0;
    int o0 = blockIdx.x * 16;
    int t = threadIdx.x;
    int wv = t >> 6, lane = t & 63;
    int rlo = lane & 15, khi = lane >> 4;
    int ibase = is * 128;

    // W load decomposition: q(8) x wol(16) x wig(4); 8 q-lanes form a 128B span
    int q = t & 7, wol = (t >> 3) & 15, wig = t >> 7;
    int whalf = q >> 2;   // 0 -> xm0 half, 1 -> xm1 half
    int y4 = q & 3;

    f32x4 acc[2][2][2];   // [h(xm)][yy][arr]
    #pragma unroll
    for (int a = 0; a < 2; ++a)
        #pragma unroll
        for (int b = 0; b < 2; ++b)
            #pragma unroll
            for (int c = 0; c < 2; ++c) acc[a][b][c] = (f32x4){0.f, 0.f, 0.f, 0.f};

    for (int ch = 0; ch < 4; ++ch) {
        int i0 = ibase + ch * 32;
        float4 fr[8];
        // load W_r: per-lane float4 at column xm0*16 + q*4 (8 q-lanes = 128B contiguous)
        #pragma unroll
        for (int u = 0; u < 8; ++u) {
            int ig = i0 + wig * 8 + u;
            fr[u] = *(const float4*)&wrp[((size_t)ig * 256 + o0 + wol) * 256 + xm0 * 16 + q * 4];
        }
        __syncthreads();
        // write Wl = xm0 (W_r) from registers; stage Xl both krows
        if (whalf == 0) {
            #pragma unroll
            for (int d = 0; d < 2; ++d)
                #pragma unroll
                for (int yy2 = 0; yy2 < 4; ++yy2) {
                    int y = y4 * 4 + yy2;
                    ushort4 pk;
                    pk.x = f2bf(((const float*)&fr[d * 4 + 0])[yy2]);
                    pk.y = f2bf(((const float*)&fr[d * 4 + 1])[yy2]);
                    pk.z = f2bf(((const float*)&fr[d * 4 + 2])[yy2]);
                    pk.w = f2bf(((const float*)&fr[d * 4 + 3])[yy2]);
                    *(ushort4*)&Wl[y * 648 + wol * 40 + wig * 8 + d * 4] = pk;
                }
        }
        {   // stage X for both krows
            #pragma unroll
            for (int s = 0; s < 4; ++s) {
                int m = t + s * 512;
                int y = m & 15, i4 = (m >> 4) & 7, b = (m >> 7) & 7, hh = (m >> 10) & 1;
                int igx = i0 + i4 * 4;
                int kr = krow0 + hh;
                float2 g[4];
                #pragma unroll
                for (int u = 0; u < 4; ++u)
                    g[u] = *(const float2*)&xft[(((size_t)(b * 256 + igx + u)) * 32 + kr) * 32 + y * 2];
                ushort4 re, im;
                re.x = f2bf(g[0].x); re.y = f2bf(g[1].x); re.z = f2bf(g[2].x); re.w = f2bf(g[3].x);
                im.x = f2bf(g[0].y); im.y = f2bf(g[1].y); im.z = f2bf(g[2].y); im.w = f2bf(g[3].y);
                *(ushort4*)&Xl[hh][b * 632 + y * 40 + i4 * 4] = re;
                *(ushort4*)&Xl[hh][(b + 8) * 632 + y * 40 + i4 * 4] = im;
            }
        }
        __syncthreads();
        // MFMA xm0, arr0
        #pragma unroll
        for (int yy = 0; yy < 2; ++yy) {
            int y = wv * 2 + yy;
            bf16x8 Bf = *(const bf16x8*)&Xl[0][rlo * 632 + y * 40 + khi * 8];
            bf16x8 Af = *(const bf16x8*)&Wl[y * 648 + rlo * 40 + khi * 8];
            acc[0][yy][0] = __builtin_amdgcn_mfma_f32_16x16x32_bf16(Af, Bf, acc[0][yy][0], 0, 0, 0);
        }
        __syncthreads();
        // write Wl = xm1 (W_r)
        if (whalf == 1) {
            #pragma unroll
            for (int d = 0; d < 2; ++d)
                #pragma unroll
                for (int yy2 = 0; yy2 < 4; ++yy2) {
                    int y = y4 * 4 + yy2;
                    ushort4 pk;
                    pk.x = f2bf(((const float*)&fr[d * 4 + 0])[yy2]);
                    pk.y = f2bf(((const float*)&fr[d * 4 + 1])[yy2]);
                    pk.z = f2bf(((const float*)&fr[d * 4 + 2])[yy2]);
                    pk.w = f2bf(((const float*)&fr[d * 4 + 3])[yy2]);
                    *(ushort4*)&Wl[y * 648 + wol * 40 + wig * 8 + d * 4] = pk;
                }
        }
        __syncthreads();
        // MFMA xm1, arr0
        #pragma unroll
        for (int yy = 0; yy < 2; ++yy) {
            int y = wv * 2 + yy;
            bf16x8 Bf = *(const bf16x8*)&Xl[1][rlo * 632 + y * 40 + khi * 8];
            bf16x8 Af = *(const bf16x8*)&Wl[y * 648 + rlo * 40 + khi * 8];
            acc[1][yy][0] = __builtin_amdgcn_mfma_f32_16x16x32_bf16(Af, Bf, acc[1][yy][0], 0, 0, 0);
        }
        // load W_i (fr reused; W_r values fully consumed)
        #pragma unroll
        for (int u = 0; u < 8; ++u) {
            int ig = i0 + wig * 8 + u;
            fr[u] = *(const float4*)&wip[((size_t)ig * 256 + o0 + wol) * 256 + xm0 * 16 + q * 4];
        }
        __syncthreads();
        // write Wl = xm0 (W_i)
        if (whalf == 0) {
            #pragma unroll
            for (int d = 0; d < 2; ++d)
                #pragma unroll
                for (int yy2 = 0; yy2 < 4; ++yy2) {
                    int y = y4 * 4 + yy2;
                    ushort4 pk;
                    pk.x = f2bf(((const float*)&fr[d * 4 + 0])[yy2]);
                    pk.y = f2bf(((const float*)&fr[d * 4 + 1])[yy2]);
                    pk.z = f2bf(((const float*)&fr[d * 4 + 2])[yy2]);
                    pk.w = f2bf(((const float*)&fr[d * 4 + 3])[yy2]);
                    *(ushort4*)&Wl[y * 648 + wol * 40 + wig * 8 + d * 4] = pk;
                }
        }
        __syncthreads();
        // MFMA xm0, arr1
        #pragma unroll
        for (int yy = 0; yy < 2; ++yy) {
            int y = wv * 2 + yy;
            bf16x8 Bf = *(const bf16x8*)&Xl[0][rlo * 632 + y * 40 + khi * 8];
            bf16x8 Af = *(const bf16x8*)&Wl[y * 648 + rlo * 40 + khi * 8];
            acc[0][yy][1] = __builtin_amdgcn_mfma_f32_16x16x32_bf16(Af, Bf, acc[0][yy][1], 0, 0, 0);
        }
        __syncthreads();
        // write Wl = xm1 (W_i)
        if (whalf == 1) {
            #pragma unroll
            for (int d = 0; d < 2; ++d)
                #pragma unroll
                for (int yy2 = 0; yy2 < 4; ++yy2) {
                    int y = y4 * 4 + yy2;
                    ushort4 pk;
                    pk.x = f2bf(((const float*)&fr[d * 4 + 0])[yy2]);
                    pk.y = f2bf(((const float*)&fr[d * 4 + 1])[yy2]);
                    pk.z = f2bf(((const float*)&fr[d * 4 + 2])[yy2]);
                    pk.w = f2bf(((const float*)&fr[d * 4 + 3])[yy2]);
                    *(ushort4*)&Wl[y * 648 + wol * 40 + wig * 8 + d * 4] = pk;
                }
        }
        __syncthreads();
        // MFMA xm1, arr1
        #pragma unroll
        for (int yy = 0; yy < 2; ++yy) {
            int y = wv * 2 + yy;
            bf16x8 Bf = *(const bf16x8*)&Xl[1][rlo * 632 + y * 40 + khi * 8];
            bf16x8 Af = *(const bf16x8*)&Wl[y * 648 + rlo * 40 + khi * 8];
            acc[1][yy][1] = __builtin_amdgcn_mfma_f32_16x16x32_bf16(Af, Bf, acc[1][yy][1], 0, 0, 0);
        }
    }

    // epilogue: re = C1[b] - C2[b+8]; im = C2[b] + C1[b+8], per xm of the pair
    float* dp = part + (size_t)is * 4194304;
    int bb = rlo & 7, hi = rlo >> 3;
    #pragma unroll
    for (int h = 0; h < 2; ++h) {
        int krow = krow0 + h;
        #pragma unroll
        for (int yy = 0; yy < 2; ++yy) {
            int y = wv * 2 + yy;
            #pragma unroll
            for (int j = 0; j < 4; ++j) {
                float C1 = acc[h][yy][0][j];
                float c2x = __shfl_xor(acc[h][yy][1][j], 8);
                float val = hi ? (c2x + C1) : (C1 - c2x);
                int o = o0 + khi * 4 + j;
                dp[(((size_t)(bb * 256 + o) * 32 + krow) * 16 + y) * 2 + hi] = val;
            }
        }
    }
}

// 256-thread irfft2 + gelu(x1 + conv); sums 2 partials; twiddles hoisted.
__global__ void __launch_bounds__(256) k_irfft_fuse(const float* __restrict__ part,
        const ushort* __restrict__ x2t, ushort* __restrict__ tmp) {
    __shared__ float F[32][16][2];
    __shared__ alignas(16) float tre[16][68], tim[16][68];
    __shared__ float twc[64], tws[64];
    int p = blockIdx.x;
    int t = threadIdx.x;
    int h = t & 63, grp = t >> 6;
    const float2* s0 = (const float2*)part + (size_t)p * 512;
    #pragma unroll
    for (int l = 0; l < 2; ++l) {
        int idx = t + l * 256;
        float2 a = s0[idx];
        float2 b2 = s0[idx + 2097152];
        ((float2*)F)[idx] = make_float2(a.x + b2.x, a.y + b2.y);
    }
    if (t < 64) {
        twc[t] = cosf((float)t * (6.283185307179586f / 64.0f));
        tws[t] = sinf((float)t * (6.283185307179586f / 64.0f));
    }
    __syncthreads();
    {
        float reA[4], imA[4];
        #pragma unroll
        for (int q = 0; q < 4; ++q) { reA[q] = 0.f; imA[q] = 0.f; }
        #pragma unroll
        for (int krow = 0; krow < 32; ++krow) {
            int kh = krow < 16 ? krow : krow + 32;
            int j = (h * kh) & 63;
            float c = twc[j], s = tws[j];
            #pragma unroll
            for (int q = 0; q < 4; ++q) {
                int kw = grp + q * 4;
                float fr = F[krow][kw][0], fi = F[krow][kw][1];
                reA[q] += fr * c - fi * s;
                imA[q] += fr * s + fi * c;
            }
        }
        #pragma unroll
        for (int q = 0; q < 4; ++q) {
            int kw = grp + q * 4;
            tre[kw][h] = reA[q] * (1.f / 64.f);
            tim[kw][h] = imA[q] * (1.f / 64.f);
        }
    }
    __syncthreads();
    int w = h;
    float twcr[15], twsr[15];
    #pragma unroll
    for (int kw = 1; kw < 16; ++kw) {
        int j = (w * kw) & 63;
        twcr[kw - 1] = 2.f * twc[j];
        twsr[kw - 1] = 2.f * tws[j];
    }
    float accv[16];
    #pragma unroll
    for (int v4 = 0; v4 < 4; ++v4) {
        float4 tr = *(const float4*)&tre[0][grp * 16 + v4 * 4];
        accv[v4 * 4 + 0] = tr.x; accv[v4 * 4 + 1] = tr.y;
        accv[v4 * 4 + 2] = tr.z; accv[v4 * 4 + 3] = tr.w;
    }
    #pragma unroll
    for (int kw = 1; kw < 16; ++kw) {
        float c = twcr[kw - 1], s = twsr[kw - 1];
        #pragma unroll
        for (int v4 = 0; v4 < 4; ++v4) {
            float4 tr = *(const float4*)&tre[kw][grp * 16 + v4 * 4];
            float4 ti = *(const float4*)&tim[kw][grp * 16 + v4 * 4];
            accv[v4 * 4 + 0] += tr.x * c - ti.x * s;
            accv[v4 * 4 + 1] += tr.y * c - ti.y * s;
            accv[v4 * 4 + 2] += tr.z * c - ti.z * s;
            accv[v4 * 4 + 3] += tr.w * c - ti.w * s;
        }
    }
    const ushort* x2p = x2t + (size_t)p * 4096;
    ushort* tp = tmp + (size_t)p * 4096;
    #pragma unroll
    for (int qq = 0; qq < 16; ++qq) {
        int qrow = grp * 16 + qq;
        float x1 = accv[qq] * (1.f / 64.f);
        int idx = qrow * 64 + w;
        tp[idx] = f2bf(gelu_f(x1 + b2f(x2p[idx])));
    }
}

// transpose tmp(bf16) [b][d][n] -> e0t bf16 [b][n][d] (no residual/cw)
__global__ void k_fno_final(const ushort* __restrict__ tmp, ushort* __restrict__ e0t) {
    __shared__ ushort tile[32][34];
    int b = blockIdx.z;
    int n0 = blockIdx.x * 32, d0 = blockIdx.y * 32;
    int tx = threadIdx.x, ty = threadIdx.y;
    const ushort* tb = tmp + (size_t)b * DD * NN;
    #pragma unroll
    for (int i = 0; i < 4; ++i)
        tile[ty + i * 8][tx] = tb[(size_t)(d0 + ty + i * 8) * NN + n0 + tx];
    __syncthreads();
    #pragma unroll
    for (int i = 0; i < 4; ++i) {
        int n = n0 + ty + i * 8, d = d0 + tx;
        e0t[((size_t)b * NN + n) * DD + d] = tile[tx][ty + i * 8];
    }
}

// ---------------- layernorm (bf16 in, bf16 out) ----------------
__global__ void __launch_bounds__(256) k_ln(const ushort* __restrict__ in, const float* __restrict__ g,
        const float* __restrict__ be, ushort* __restrict__ outb) {
    int row = blockIdx.x * 4 + (threadIdx.x >> 6);
    int lane = threadIdx.x & 63;
    ushort4 u = ((const ushort4*)(in + (size_t)row * 256))[lane];
    float4 v = make_float4(b2f(u.x), b2f(u.y), b2f(u.z), b2f(u.w));
    float s = v.x + v.y + v.z + v.w;
    float s2 = v.x * v.x + v.y * v.y + v.z * v.z + v.w * v.w;
    #pragma unroll
    for (int off = 32; off > 0; off >>= 1) {
        s += __shfl_down(s, off);
        s2 += __shfl_down(s2, off);
    }
    s = __shfl(s, 0); s2 = __shfl(s2, 0);
    float mu = s * (1.f / 256.f);
    float var = s2 * (1.f / 256.f) - mu * mu;
    float rstd = rsqrtf(var + 1e-5f);
    float4 gv = ((const float4*)g)[lane];
    float4 bv = ((const float4*)be)[lane];
    ushort4 ov;
    ov.x = f2bf((v.x - mu) * rstd * gv.x + bv.x);
    ov.y = f2bf((v.y - mu) * rstd * gv.y + bv.y);
    ov.z = f2bf((v.z - mu) * rstd * gv.z + bv.z);
    ov.w = f2bf((v.w - mu) * rstd * gv.w + bv.w);
    ((ushort4*)(outb + (size_t)row * 256))[lane] = ov;
}

// ---------------- MFMA window attention ----------------
__global__ void __launch_bounds__(256) k_window_attn(const ushort* __restrict__ qkvb,
        ushort* __restrict__ aob) {
    __shared__ ushort lds[4 * 7424];
    int t = threadIdx.x;
    int w = t >> 6, lane = t & 63;
    int wi = blockIdx.x, hh = blockIdx.y;
    int hd = hh * 4 + w;
    int b = wi >> 6, hb = (wi >> 3) & 7, wb = wi & 7;
    ushort* A = lds + w * 7424;
    ushort* Kl = A + 2560;
    ushort* Vt = A + 5120;
    int rlo = lane & 15, kq = lane >> 4;

    int tok = lane;
    int n = hb * 512 + wb * 8 + ((tok >> 3) << 6) + (tok & 7);
    const ushort* gq = qkvb + ((size_t)b * 4096 + n) * 768 + hd * 32;
    const uint4* qp = (const uint4*)gq;
    const uint4* kp = (const uint4*)(gq + 256);
    const uint4* vp = (const uint4*)(gq + 512);
    uint4 q0 = qp[0], q1 = qp[1], q2 = qp[2], q3 = qp[3];
    uint4 k0 = kp[0], k1 = kp[1], k2 = kp[2], k3 = kp[3];
    uint4 v0 = vp[0], v1 = vp[1], v2 = vp[2], v3 = vp[3];
    uint4* qr = (uint4*)(A + tok * 40);
    qr[0] = q0; qr[1] = q1; qr[2] = q2; qr[3] = q3;
    uint4* kr = (uint4*)(Kl + tok * 40);
    kr[0] = k0; kr[1] = k1; kr[2] = k2; kr[3] = k3;
    ushort vbuf[32];
    *(uint4*)&vbuf[0] = v0; *(uint4*)&vbuf[8] = v1;
    *(uint4*)&vbuf[16] = v2; *(uint4*)&vbuf[24] = v3;
    #pragma unroll
    for (int d = 0; d < 32; ++d) Vt[d * 72 + tok] = vbuf[d];
    __syncthreads();

    bf16x8 Qf[4], Kf[4];
    #pragma unroll
    for (int lt = 0; lt < 4; ++lt)
        Qf[lt] = *(const bf16x8*)(A + (lt * 16 + rlo) * 40 + kq * 8);
    #pragma unroll
    for (int mt = 0; mt < 4; ++mt)
        Kf[mt] = *(const bf16x8*)(Kl + (mt * 16 + rlo) * 40 + kq * 8);

    f32x4 S[4][4];
    #pragma unroll
    for (int lt = 0; lt < 4; ++lt)
        #pragma unroll
        for (int mt = 0; mt < 4; ++mt)
            S[lt][mt] = __builtin_amdgcn_mfma_f32_16x16x32_bf16(Qf[lt], Kf[mt],
                        (f32x4){0.f, 0.f, 0.f, 0.f}, 0, 0, 0);
    __syncthreads();

    const float scale = 0.17677669529663687f;
    float inv_[4][4];
    #pragma unroll
    for (int lt = 0; lt < 4; ++lt) {
        float m4[4], s4[4];
        #pragma unroll
        for (int j = 0; j < 4; ++j) {
            m4[j] = fmaxf(fmaxf(S[lt][0][j], S[lt][1][j]), fmaxf(S[lt][2][j], S[lt][3][j]));
        }
        #pragma unroll
        for (int off = 1; off < 16; off <<= 1)
            #pragma unroll
            for (int j = 0; j < 4; ++j) m4[j] = fmaxf(m4[j], __shfl_xor(m4[j], off));
        #pragma unroll
        for (int j = 0; j < 4; ++j) s4[j] = 0.f;
        #pragma unroll
        for (int mt = 0; mt < 4; ++mt)
            #pragma unroll
            for (int j = 0; j < 4; ++j) {
                float p = __expf((S[lt][mt][j] - m4[j]) * scale);
                s4[j] += p;
                A[(lt * 16 + kq * 4 + j) * 72 + mt * 16 + rlo] = f2bf(p);
            }
        #pragma unroll
        for (int off = 1; off < 16; off <<= 1)
            #pragma unroll
            for (int j = 0; j < 4; ++j) s4[j] += __shfl_xor(s4[j], off);
        #pragma unroll
        for (int j = 0; j < 4; ++j) inv_[lt][j] = 1.0f / s4[j];
    }
    __syncthreads();

    f32x4 O[4][2];
    #pragma unroll
    for (int lt = 0; lt < 4; ++lt)
        #pragma unroll
        for (int dt = 0; dt < 2; ++dt) {
            f32x4 o = (f32x4){0.f, 0.f, 0.f, 0.f};
            #pragma unroll
            for (int mc = 0; mc < 2; ++mc) {
                bf16x8 pa = *(const bf16x8*)(A + (lt * 16 + rlo) * 72 + mc * 32 + kq * 8);
                bf16x8 vb = *(const bf16x8*)(Vt + (dt * 16 + rlo) * 72 + mc * 32 + kq * 8);
                o = __builtin_amdgcn_mfma_f32_16x16x32_bf16(pa, vb, o, 0, 0, 0);
            }
            O[lt][dt] = o;
        }
    __syncthreads();

    #pragma unroll
    for (int lt = 0; lt < 4; ++lt)
        #pragma unroll
        for (int dt = 0; dt < 2; ++dt)
            #pragma unroll
            for (int j = 0; j < 4; ++j)
                A[(lt * 16 + kq * 4 + j) * 40 + dt * 16 + rlo] = f2bf(O[lt][dt][j] * inv_[lt][j]);
    __syncthreads();
    const uint4* orow = (const uint4*)(A + lane * 40);
    uint4 o0 = orow[0], o1 = orow[1], o2 = orow[2], o3 = orow[3];
    uint4* gout = (uint4*)(aob + ((size_t)b * 4096 + n) * 256 + hd * 32);
    gout[0] = o0; gout[1] = o1; gout[2] = o2; gout[3] = o3;
}

extern "C" void kernel_launch(void* const* d_in, const int* in_sizes, int n_in,
                              void* d_out, int out_size, void* d_ws, size_t ws_size,
                              hipStream_t stream) {
    (void)in_sizes; (void)n_in; (void)out_size; (void)ws_size;
    const float* x        = (const float*)d_in[0];
    const float* text     = (const float*)d_in[1];
    const float* gate_w1  = (const float*)d_in[2];
    const float* gate_b1  = (const float*)d_in[3];
    const float* gate_w2  = (const float*)d_in[4];
    const float* gate_b2  = (const float*)d_in[5];
    const float* fno_w1r  = (const float*)d_in[6];
    const float* fno_w1i  = (const float*)d_in[7];
    const float* fno_w2r  = (const float*)d_in[8];
    const float* fno_w2i  = (const float*)d_in[9];
    const float* fno_cw   = (const float*)d_in[10];
    const float* fno_cb   = (const float*)d_in[11];
    const float* mlp1_w1  = (const float*)d_in[12];
    const float* mlp1_b1  = (const float*)d_in[13];
    const float* mlp1_w2  = (const float*)d_in[14];
    const float* mlp1_b2  = (const float*)d_in[15];
    const float* mlp2_w1  = (const float*)d_in[16];
    const float* mlp2_b1  = (const float*)d_in[17];
    const float* mlp2_w2  = (const float*)d_in[18];
    const float* mlp2_b2  = (const float*)d_in[19];
    const float* ln1_g    = (const float*)d_in[20];
    const float* ln1_b    = (const float*)d_in[21];
    const float* qkv_w    = (const float*)d_in[22];
    const float* qkv_b    = (const float*)d_in[23];
    const float* out_w    = (const float*)d_in[24];
    const float* out_b    = (const float*)d_in[25];
    const float* ln2_g    = (const float*)d_in[26];
    const float* ln2_b    = (const float*)d_in[27];
    const float* wa_w1    = (const float*)d_in[28];
    const float* wa_b1    = (const float*)d_in[29];
    const float* wa_w2    = (const float*)d_in[30];
    const float* wa_b2    = (const float*)d_in[31];

    float* ws   = (float*)d_ws;
    float* h1   = ws + 8192;         // 2048
    float* cwp  = ws + 10240;        // 32
    ushort* wbf = (ushort*)(ws + 16384);     // weight bf16 pool
    ushort* w1aT = wbf;
    ushort* w2aT = w1aT + 262144;
    ushort* w1bT = w2aT + 262144;
    ushort* w2bT = w1bT + 262144;
    ushort* w1cT = w2bT + 262144;
    ushort* w2cT = w1cT + 262144;
    ushort* qkvT = w2cT + 262144;
    ushort* outwT = qkvT + 196608;
    ushort* convT = outwT + 65536;
    ushort* Xbf  = (ushort*)(ws + 16384 + 1048576);          // bf16 x
    float* slotA = ws + 16384 + 1048576 + 4194304;           // 8.39M floats
    float* xft   = slotA + 8388608;                          // 2.1M
    float* oft   = xft + 2097152;                            // 2.1M
    float* regD  = oft + 2097152;                            // 8.39M
    ushort* bigb = (ushort*)(regD + 8388608);                // tmp/qkv/hidden bf16
    float* gpart = oft;     // 262144 floats (gating phase only)

    // timeline-reused bf16 buffers
    ushort* xgb   = (ushort*)slotA;                // xg bf16 (FNO)
    ushort* g1b   = (ushort*)slotA;                // expert1 gemm2 out (after FNO)
    ushort* g2b   = (ushort*)(slotA + 4194304);    // expert2 gemm2 out
    ushort* x2tb  = (ushort*)regD;                 // conv branch bf16
    ushort* e0tb  = (ushort*)regD;                 // fno transposed out (after irfft)
    ushort* scr   = (ushort*)(regD + 4194304);     // ln-out / attn_o / ln2-out
    ushort* xatb  = (ushort*)xft;                  // xattn bf16 (xft+oft region, after spectral)

    float* outp = (float*)d_out;
    float* wout = outp + (size_t)NB * NN * DD;

    // fused conversion + transpose + gate-mean partials, then gating
    k_cvt_gate_t<<<dim3(128, 8, 8), dim3(32, 8), 0, stream>>>(x, Xbf, xgb, gpart);
    k_gate_mm<<<dim3(8, 8), 256, 0, stream>>>(gpart, text, gate_w1, gate_b1, h1);
    k_gate_top<<<1, 64, 0, stream>>>(h1, gate_w2, gate_b2, cwp, wout);

    // prep: all weight bf16 conversions in one launch
    k_wt_all<<<dim3(256, 1, 9), dim3(32, 8), 0, stream>>>(
        mlp1_w1, mlp1_w2, mlp2_w1, mlp2_w2, wa_w1, wa_w2, qkv_w, out_w, fno_cw,
        w1aT, w2aT, w1bT, w2bT, w1cT, w2cT, qkvT, outwT, convT);

    // expert 0: FNO -> e0tb (pure gelu-term, bf16, row-major)
    k_rfft2<<<2048, 256, 0, stream>>>(xgb, xft);
    k_gemm<5><<<dim3(2, 32, 8), 256, 0, stream>>>(convT, Xbf, fno_cb, nullptr, nullptr,
        x2tb, nullptr, 0, 256, 4096, 0, (size_t)NN * DD, (size_t)DD * NN,
        nullptr, nullptr, nullptr, nullptr);
    k_spectral<<<dim3(16, 8, 4), 512, 0, stream>>>(xft, fno_w1r, fno_w1i, fno_w2r, fno_w2i, slotA);
    k_irfft_fuse<<<2048, 256, 0, stream>>>(slotA, x2tb, bigb);
    k_fno_final<<<dim3(128, 8, 8), dim3(32, 8), 0, stream>>>(bigb, e0tb);

    // expert 1: MLP -> g1b
    k_gemm<0><<<dim3(256, 8), 256, 0, stream>>>(Xbf, w1aT, mlp1_b1, nullptr, nullptr, bigb, nullptr, 0, 256, 1024, 0, 0, 0, nullptr, nullptr, nullptr, nullptr);
    k_gemm<1><<<dim3(256, 2), 256, 0, stream>>>(bigb, w2aT, mlp1_b2, nullptr, nullptr, g1b, nullptr, 0, 1024, 256, 0, 0, 0, nullptr, nullptr, nullptr, nullptr);

    // expert 2: window attention -> xatb (residual stream) and g2b (mlp out)
    k_ln<<<8192, 256, 0, stream>>>(Xbf, ln1_g, ln1_b, scr);
    k_gemm<1><<<dim3(256, 6), 256, 0, stream>>>(scr, qkvT, qkv_b, nullptr, nullptr, bigb, nullptr, 0, 256, 768, 0, 0, 0, nullptr, nullptr, nullptr, nullptr);
    k_window_attn<<<dim3(512, 2), 256, 0, stream>>>(bigb, scr);
    k_gemm<6><<<dim3(256, 2), 256, 0, stream>>>(scr, outwT, out_b, Xbf, nullptr, xatb, nullptr, 0, 256, 256, 0, 0, 0, nullptr, nullptr, nullptr, nullptr);
    k_ln<<<8192, 256, 0, stream>>>(xatb, ln2_g, ln2_b, scr);
    k_gemm<0><<<dim3(256, 8), 256, 0, stream>>>(scr, w1cT, wa_b1, nullptr, nullptr, bigb, nullptr, 0, 256, 1024, 0, 0, 0, nullptr, nullptr, nullptr, nullptr);
    k_gemm<1><<<dim3(256, 2), 256, 0, stream>>>(bigb, w2cT, wa_b2, nullptr, nullptr, g2b, nullptr, 0, 1024, 256, 0, 0, 0, nullptr, nullptr, nullptr, nullptr);

    // expert 3: MLP, gemm2 fuses the final combine and writes out directly
    k_gemm<0><<<dim3(256, 8), 256, 0, stream>>>(Xbf, w1bT, mlp2_b1, nullptr, nullptr, bigb, nullptr, 0, 256, 1024, 0, 0, 0, nullptr, nullptr, nullptr, nullptr);
    k_gemm<7><<<dim3(256, 2), 256, 0, stream>>>(bigb, w2bT, mlp2_b2, Xbf, outp, nullptr, cwp, 3, 1024, 256, 0, 0, 0, e0tb, g1b, g2b, xatb);
}

// Round 22
// 557.562 us; speedup vs baseline: 1.0129x; 1.0129x over previous
//
#include <hip/hip_runtime.h>
#include <math.h>

// MoEProcessor: B=8, N=4096, D=256, H=W=64, WS=8, NH=8, M=16, E=4, TD=768, HID=1024, TK=2
// Round 22: revert to R20 (best measured: 560.9 us). R21's xm-pairing refuted the
// granule hypothesis and regressed; spectral is pattern-pinned at ~2 TB/s.

#define NB 8
#define NN 4096
#define DD 256

typedef __attribute__((ext_vector_type(8))) short bf16x8;
typedef __attribute__((ext_vector_type(4))) float f32x4;

__device__ __forceinline__ float gelu_f(float v) {
    float u = v * (1.0f + 0.044715f * v * v);
    float e = __expf(-1.5957691f * u);
    return v * __builtin_amdgcn_rcpf(1.0f + e);
}
__device__ __forceinline__ ushort f2bf(float f) {
    uint32_t u = __float_as_uint(f);
    uint32_t r = (u + 0x7fffu + ((u >> 16) & 1u)) >> 16;
    return (ushort)r;
}
__device__ __forceinline__ float b2f(ushort h) {
    return __uint_as_float(((uint32_t)h) << 16);
}

// ---------------- fused x->bf16 + transpose + gate-mean partials ----------------
__global__ void k_cvt_gate_t(const float* __restrict__ src, ushort* __restrict__ xbf,
        ushort* __restrict__ xg, float* __restrict__ gp) {
    __shared__ ushort tile[32][34];
    __shared__ float sred[8][32];
    int nt = blockIdx.x, dt = blockIdx.y, b = blockIdx.z;
    int tx = threadIdx.x, ty = threadIdx.y;
    int n0 = nt * 32, d0 = dt * 32;
    const float* xb = src + ((size_t)b * NN + n0) * DD + d0;
    ushort* xbb = xbf + ((size_t)b * NN + n0) * DD + d0;
    float s = 0.f;
    #pragma unroll
    for (int i = 0; i < 4; ++i) {
        int r = ty + i * 8;
        float v = xb[(size_t)r * DD + tx];
        ushort h = f2bf(v);
        xbb[(size_t)r * DD + tx] = h;
        tile[r][tx] = h;
        s += v;
    }
    sred[ty][tx] = s;
    __syncthreads();
    ushort* xgb = xg + (size_t)b * DD * NN;
    #pragma unroll
    for (int i = 0; i < 4; ++i) {
        int d = d0 + ty + i * 8;
        xgb[(size_t)d * NN + n0 + tx] = tile[tx][ty + i * 8];
    }
    if (ty == 0) {
        float tot = 0.f;
        #pragma unroll
        for (int j = 0; j < 8; ++j) tot += sred[j][tx];
        gp[(((size_t)b * 8 + dt) * 128 + nt) * 32 + tx] = tot;
    }
}

// gate mean-reduce + mlp1, parallel over j-tiles: grid (8 jt, 8 b), block 256.
__global__ void __launch_bounds__(256) k_gate_mm(const float* __restrict__ gp,
        const float* __restrict__ text, const float* __restrict__ w1,
        const float* __restrict__ b1, float* __restrict__ h1) {
    __shared__ float fs[1024];
    __shared__ float sred[8][32];
    int jt = blockIdx.x, b = blockIdx.y;
    int t = threadIdx.x;
    {
        int dt = t >> 5, tx = t & 31;
        const float* base = gp + ((size_t)b * 8 + dt) * 128 * 32 + tx;
        float s = 0.f;
        for (int j = 0; j < 128; j += 4) {
            s += base[(j + 0) * 32] + base[(j + 1) * 32]
               + base[(j + 2) * 32] + base[(j + 3) * 32];
        }
        fs[t] = s * (1.0f / NN);
        for (int j = t; j < 768; j += 256) fs[256 + j] = text[b * 768 + j];
    }
    __syncthreads();
    int jl = t & 31, ks = t >> 5;
    int j = jt * 32 + jl;
    float acc = 0.f;
    int k0 = ks * 128;
    for (int k = k0; k < k0 + 128; ++k) acc += fs[k] * w1[k * 256 + j];
    sred[ks][jl] = acc;
    __syncthreads();
    if (t < 32) {
        float s = b1[jt * 32 + t];
        #pragma unroll
        for (int q = 0; q < 8; ++q) s += sred[q][t];
        h1[b * 256 + jt * 32 + t] = fmaxf(s, 0.f);
    }
}

__global__ void k_gate_top(const float* __restrict__ h1, const float* __restrict__ w2,
                           const float* __restrict__ b2, float* __restrict__ cw,
                           float* __restrict__ wout) {
    __shared__ float lg[8][4];
    int t = threadIdx.x;
    if (t < 32) {
        int b = t >> 2, e = t & 3;
        float acc = b2[e];
        const float* h = h1 + b * 256;
        for (int k = 0; k < 256; ++k) acc += h[k] * w2[k * 4 + e];
        lg[b][e] = acc;
    }
    __syncthreads();
    if (t < 8) {
        int b = t;
        float v[4];
        #pragma unroll
        for (int e = 0; e < 4; ++e) v[e] = lg[b][e];
        int i0 = 0;
        #pragma unroll
        for (int e = 1; e < 4; ++e) if (v[e] > v[i0]) i0 = e;
        int i1 = -1;
        #pragma unroll
        for (int e = 0; e < 4; ++e) {
            if (e == i0) continue;
            if (i1 < 0 || v[e] > v[i1]) i1 = e;
        }
        float v0 = v[i0], v1 = v[i1];
        float e1v = expf(v1 - v0);
        float inv = 1.0f / (1.0f + e1v);
        float w0 = inv, w1v = e1v * inv;
        wout[b * 2 + 0] = w0;
        wout[b * 2 + 1] = w1v;
        float c[4] = {0.f, 0.f, 0.f, 0.f};
        c[i0] += w0; c[i1] += w1v;
        #pragma unroll
        for (int e = 0; e < 4; ++e) cw[b * 4 + e] = c[e];
    }
}

// batched transpose+convert: 9 jobs, grid (256, 1, 9), block (32,8)
__global__ void k_wt_all(const float* s0, const float* s1, const float* s2,
        const float* s3, const float* s4, const float* s5, const float* s6,
        const float* s7, const float* s8,
        ushort* d0, ushort* d1, ushort* d2, ushort* d3, ushort* d4,
        ushort* d5, ushort* d6, ushort* d7, ushort* d8) {
    const float* srcs[9] = {s0, s1, s2, s3, s4, s5, s6, s7, s8};
    ushort* dsts[9] = {d0, d1, d2, d3, d4, d5, d6, d7, d8};
    const int Ks[9] = {256, 1024, 256, 1024, 256, 1024, 256, 256, 256};
    const int Ns[9] = {1024, 256, 1024, 256, 1024, 256, 768, 256, 256};
    __shared__ float tile[32][33];
    int j = blockIdx.z;
    int K = Ks[j], N = Ns[j];
    int tn = N >> 5, tk = K >> 5;
    int tid = blockIdx.x;
    if (tid >= tn * tk) return;
    int n0 = (tid % tn) * 32, k0 = (tid / tn) * 32;
    const float* src = srcs[j];
    ushort* dst = dsts[j];
    int tx = threadIdx.x, ty = threadIdx.y;
    #pragma unroll
    for (int i = 0; i < 4; ++i)
        tile[ty + i * 8][tx] = src[(size_t)(k0 + ty + i * 8) * N + n0 + tx];
    __syncthreads();
    #pragma unroll
    for (int i = 0; i < 4; ++i)
        dst[(size_t)(n0 + ty + i * 8) * K + k0 + tx] = f2bf(tile[tx][ty + i * 8]);
}

// ---------------- MFMA GEMM ----------------
// MODE 0: outb = bf16(gelu(acc+colbias))
// MODE 1: outb = bf16(acc+colbias)
// MODE 5: outb = bf16(acc+rowbias)  (batched)
// MODE 6: outb = bf16(acc+colbias + bf16res)
// MODE 7: outf = combine(acc+colbias, e0p, g1p, g2p, xap, res=xbf, cw)  [final]
template<int MODE>
__global__ void __launch_bounds__(256) k_gemm(const ushort* __restrict__ A,
        const ushort* __restrict__ Bt, const float* __restrict__ bias,
        const void* __restrict__ res, float* __restrict__ outf,
        ushort* __restrict__ outb, const float* __restrict__ cw, int eidx,
        int K, int Ncols, size_t bsA, size_t bsB, size_t bsC,
        const ushort* __restrict__ e0p, const ushort* __restrict__ g1p,
        const ushort* __restrict__ g2p, const ushort* __restrict__ xap) {
    __shared__ alignas(16) char smem[34816];   // staging 32KB; epilogue [128][136] ushort
    ushort* sA = (ushort*)smem;            // [2][4096]
    ushort* sB = (ushort*)(smem + 16384);  // [2][4096]
    int z = blockIdx.z;
    A += z * bsA; Bt += z * bsB;
    if (outf) outf += z * bsC;
    if (outb) outb += z * bsC;
    int m0 = blockIdx.x * 128;
    int n0 = blockIdx.y * 128;
    int t = threadIdx.x;
    int lane = t & 63, wid = t >> 6;
    int wr = wid >> 1, wc = wid & 1;
    int rlo = lane & 15, khi = (lane >> 4) * 8;

    auto stage = [&](int buf, int k0) {
        const ushort* Ab = A + (size_t)m0 * K + k0;
        const ushort* Bb = Bt + (size_t)n0 * K + k0;
        #pragma unroll
        for (int h = 0; h < 2; ++h) {
            int s = t + h * 256;
            int row = s >> 2, kc = (s & 3) * 8;
            __builtin_amdgcn_global_load_lds(
                (const __attribute__((address_space(1))) void*)(Ab + (size_t)row * K + kc),
                (__attribute__((address_space(3))) void*)(sA + buf * 4096 + s * 8),
                16, 0, 0);
            __builtin_amdgcn_global_load_lds(
                (const __attribute__((address_space(1))) void*)(Bb + (size_t)row * K + kc),
                (__attribute__((address_space(3))) void*)(sB + buf * 4096 + s * 8),
                16, 0, 0);
        }
    };

    f32x4 acc[4][4];
    #pragma unroll
    for (int i = 0; i < 4; ++i)
        #pragma unroll
        for (int j = 0; j < 4; ++j) acc[i][j] = (f32x4){0.f, 0.f, 0.f, 0.f};

    int KT = K >> 5;
    stage(0, 0);
    int cur = 0;
    for (int kt = 0; kt < KT; ++kt) {
        __syncthreads();
        if (kt + 1 < KT) stage(cur ^ 1, (kt + 1) << 5);
        const ushort* Ap = sA + cur * 4096;
        const ushort* Bp = sB + cur * 4096;
        bf16x8 af[4], bfr[4];
        #pragma unroll
        for (int i = 0; i < 4; ++i) {
            af[i]  = *(const bf16x8*)(Ap + (wr * 64 + i * 16 + rlo) * 32 + khi);
            bfr[i] = *(const bf16x8*)(Bp + (wc * 64 + i * 16 + rlo) * 32 + khi);
        }
        #pragma unroll
        for (int i = 0; i < 4; ++i)
            #pragma unroll
            for (int j = 0; j < 4; ++j)
                acc[i][j] = __builtin_amdgcn_mfma_f32_16x16x32_bf16(af[i], bfr[j], acc[i][j], 0, 0, 0);
        cur ^= 1;
    }

    float bj4[4];
    if constexpr (MODE != 5) {
        #pragma unroll
        for (int nt = 0; nt < 4; ++nt) bj4[nt] = bias[n0 + wc * 64 + nt * 16 + rlo];
    }

    // single-phase epilogue: [128][136] bf16 arena, 2 barriers total
    ushort* eb = (ushort*)smem;
    __syncthreads();
    #pragma unroll
    for (int mt = 0; mt < 4; ++mt) {
        int row0 = wr * 64 + mt * 16 + (lane >> 4) * 4;
        #pragma unroll
        for (int nt = 0; nt < 4; ++nt) {
            int col = wc * 64 + nt * 16 + rlo;
            #pragma unroll
            for (int j = 0; j < 4; ++j) {
                float v = acc[mt][nt][j];
                if constexpr (MODE == 5)
                    v += bias[m0 + row0 + j];
                else
                    v += bj4[nt];
                if (MODE == 0) v = gelu_f(v);
                eb[(row0 + j) * 136 + col] = f2bf(v);
            }
        }
    }
    __syncthreads();
    const ushort* resb = (const ushort*)res;
    #pragma unroll
    for (int h = 0; h < 8; ++h) {
        int s = t + h * 256;
        int r = s >> 4, c = (s & 15) * 8;
        int grow = m0 + r;
        size_t off = (size_t)grow * Ncols + n0 + c;
        if constexpr (MODE == 6) {
            ushort ee[8], rr[8], oo[8];
            *(uint4*)ee = *(uint4*)&eb[r * 136 + c];
            *(uint4*)rr = *(const uint4*)(resb + off);
            #pragma unroll
            for (int q = 0; q < 8; ++q) oo[q] = f2bf(b2f(ee[q]) + b2f(rr[q]));
            *(uint4*)(outb + off) = *(uint4*)oo;
        } else if constexpr (MODE == 7) {
            int bb = grow >> 12;
            float c0 = cw[bb * 4 + 0], c1 = cw[bb * 4 + 1];
            float c2 = cw[bb * 4 + 2], c3 = cw[bb * 4 + 3];
            float cx = c0 + c1 + c3;
            ushort ee[8], a0[8], a1[8], a2[8], xa[8], xb[8];
            *(uint4*)ee = *(uint4*)&eb[r * 136 + c];
            *(uint4*)a0 = *(const uint4*)(e0p + off);
            *(uint4*)a1 = *(const uint4*)(g1p + off);
            *(uint4*)a2 = *(const uint4*)(g2p + off);
            *(uint4*)xa = *(const uint4*)(xap + off);
            *(uint4*)xb = *(const uint4*)(resb + off);
            float ov[8];
            #pragma unroll
            for (int q = 0; q < 8; ++q)
                ov[q] = c0 * b2f(a0[q]) + c1 * b2f(a1[q]) + c2 * (b2f(a2[q]) + b2f(xa[q]))
                      + c3 * b2f(ee[q]) + cx * b2f(xb[q]);
            *(float4*)(outf + off) = *(float4*)&ov[0];
            *(float4*)(outf + off + 4) = *(float4*)&ov[4];
        } else {
            *(uint4*)(outb + off) = *(uint4*)&eb[r * 136 + c];
        }
    }
}

// ---------------- FNO ----------------
// 256-thread rfft2 on bf16 plane input
__global__ void __launch_bounds__(256) k_rfft2(const ushort* __restrict__ xg, float* __restrict__ xft) {
    __shared__ float plane[64][65];
    __shared__ float s1re[16][66], s1im[16][66];
    __shared__ float twc[64], tws[64];
    int p = blockIdx.x;
    int t = threadIdx.x;
    int tx = t & 63, grp = t >> 6;
    const ushort* src = xg + (size_t)p * 4096;
    #pragma unroll
    for (int i = 0; i < 16; ++i) {
        int row = grp * 16 + i;
        plane[row][tx] = b2f(src[row * 64 + tx]);
    }
    if (t < 64) {
        twc[t] = cosf((float)t * (6.283185307179586f / 64.0f));
        tws[t] = sinf((float)t * (6.283185307179586f / 64.0f));
    }
    __syncthreads();
    int r = tx;
    #pragma unroll
    for (int q = 0; q < 4; ++q) {
        int kw = grp + q * 4;
        float re = 0.f, im = 0.f;
        for (int w = 0; w < 64; ++w) {
            int j = (w * kw) & 63;
            float xv = plane[r][w];
            re += xv * twc[j];
            im -= xv * tws[j];
        }
        s1re[kw][r] = re;
        s1im[kw][r] = im;
    }
    __syncthreads();
    float2* dst = (float2*)xft + (size_t)p * 512;
    #pragma unroll
    for (int q = 0; q < 2; ++q) {
        int oi = t + q * 256;
        int krow = oi >> 4, kw = oi & 15;
        int kh = krow < 16 ? krow : krow + 32;
        float re = 0.f, im = 0.f;
        for (int h = 0; h < 64; ++h) {
            int j = (h * kh) & 63;
            float c = twc[j], s = tws[j];
            float ar = s1re[kw][h], ai = s1im[kw][h];
            re += ar * c + ai * s;
            im += ai * c - ar * s;
        }
        dst[oi] = make_float2(re, im);
    }
}

// ---------------- MFMA spectral (R18 form: Wl 648, Xl 632, 40960 B; W_i reg prefetch) ----------------
__global__ void __launch_bounds__(512) k_spectral(const float* __restrict__ xft,
        const float* __restrict__ w1r, const float* __restrict__ w1i,
        const float* __restrict__ w2r, const float* __restrict__ w2i,
        float* __restrict__ part) {
    __shared__ alignas(16) ushort Wl[16 * 648];   // 20736 B
    __shared__ alignas(16) ushort Xl[16 * 632];   // 20224 B  (total exactly 40960)
    int z = blockIdx.z;
    int region = z >> 1, is = z & 1;
    const float* wrp = region ? w2r : w1r;
    const float* wip = region ? w2i : w1i;
    int xm = blockIdx.y;
    int krow = region * 16 + xm;
    int o0 = blockIdx.x * 16;
    int t = threadIdx.x;
    int wv = t >> 6, lane = t & 63;
    int rlo = lane & 15, khi = lane >> 4;
    int ibase = is * 128;

    int wy4 = t & 3, wol = (t >> 2) & 15, wi8 = t >> 6;

    f32x4 acc[2][2];  // [yy][arr]
    #pragma unroll
    for (int a = 0; a < 2; ++a)
        #pragma unroll
        for (int b = 0; b < 2; ++b) acc[a][b] = (f32x4){0.f, 0.f, 0.f, 0.f};

    for (int ch = 0; ch < 4; ++ch) {
        int i0 = ibase + ch * 32;
        int ig = i0 + wi8 * 4;
        // prefetch W_i into registers at chunk top (consumed after arr0 MFMA)
        float4 fi2[4];
        #pragma unroll
        for (int u = 0; u < 4; ++u)
            fi2[u] = *(const float4*)&wip[((size_t)(ig + u) * 256 + o0 + wol) * 256 + xm * 16 + wy4 * 4];
        __syncthreads();
        {   // stage W_r
            float4 f[4];
            #pragma unroll
            for (int u = 0; u < 4; ++u)
                f[u] = *(const float4*)&wrp[((size_t)(ig + u) * 256 + o0 + wol) * 256 + xm * 16 + wy4 * 4];
            #pragma unroll
            for (int yy2 = 0; yy2 < 4; ++yy2) {
                int y = wy4 * 4 + yy2;
                ushort4 pk;
                pk.x = f2bf(((const float*)&f[0])[yy2]);
                pk.y = f2bf(((const float*)&f[1])[yy2]);
                pk.z = f2bf(((const float*)&f[2])[yy2]);
                pk.w = f2bf(((const float*)&f[3])[yy2]);
                *(ushort4*)&Wl[y * 648 + wol * 40 + wi8 * 4] = pk;
            }
        }
        {   // stage X (both re/im packs)
            #pragma unroll
            for (int s = 0; s < 2; ++s) {
                int m = t + s * 512;
                int y = m & 15, i4 = (m >> 4) & 7, b = (m >> 7) & 7;
                int igx = i0 + i4 * 4;
                float2 g[4];
                #pragma unroll
                for (int u = 0; u < 4; ++u)
                    g[u] = *(const float2*)&xft[(((size_t)(b * 256 + igx + u)) * 32 + krow) * 32 + y * 2];
                ushort4 re, im;
                re.x = f2bf(g[0].x); re.y = f2bf(g[1].x); re.z = f2bf(g[2].x); re.w = f2bf(g[3].x);
                im.x = f2bf(g[0].y); im.y = f2bf(g[1].y); im.z = f2bf(g[2].y); im.w = f2bf(g[3].y);
                *(ushort4*)&Xl[b * 632 + y * 40 + i4 * 4] = re;
                *(ushort4*)&Xl[(b + 8) * 632 + y * 40 + i4 * 4] = im;
            }
        }
        __syncthreads();
        #pragma unroll
        for (int yy = 0; yy < 2; ++yy) {
            int y = wv * 2 + yy;
            bf16x8 Bf = *(const bf16x8*)&Xl[rlo * 632 + y * 40 + khi * 8];
            bf16x8 Af = *(const bf16x8*)&Wl[y * 648 + rlo * 40 + khi * 8];
            acc[yy][0] = __builtin_amdgcn_mfma_f32_16x16x32_bf16(Af, Bf, acc[yy][0], 0, 0, 0);
        }
        __syncthreads();
        {   // write W_i from prefetched registers
            #pragma unroll
            for (int yy2 = 0; yy2 < 4; ++yy2) {
                int y = wy4 * 4 + yy2;
                ushort4 pk;
                pk.x = f2bf(((const float*)&fi2[0])[yy2]);
                pk.y = f2bf(((const float*)&fi2[1])[yy2]);
                pk.z = f2bf(((const float*)&fi2[2])[yy2]);
                pk.w = f2bf(((const float*)&fi2[3])[yy2]);
                *(ushort4*)&Wl[y * 648 + wol * 40 + wi8 * 4] = pk;
            }
        }
        __syncthreads();
        #pragma unroll
        for (int yy = 0; yy < 2; ++yy) {
            int y = wv * 2 + yy;
            bf16x8 Bf = *(const bf16x8*)&Xl[rlo * 632 + y * 40 + khi * 8];
            bf16x8 Af = *(const bf16x8*)&Wl[y * 648 + rlo * 40 + khi * 8];
            acc[yy][1] = __builtin_amdgcn_mfma_f32_16x16x32_bf16(Af, Bf, acc[yy][1], 0, 0, 0);
        }
    }

    float* dp = part + (size_t)is * 4194304;
    int b = rlo & 7, hi = rlo >> 3;
    #pragma unroll
    for (int yy = 0; yy < 2; ++yy) {
        int y = wv * 2 + yy;
        #pragma unroll
        for (int j = 0; j < 4; ++j) {
            float C1 = acc[yy][0][j];
            float c2x = __shfl_xor(acc[yy][1][j], 8);
            float val = hi ? (c2x + C1) : (C1 - c2x);
            int o = o0 + khi * 4 + j;
            dp[(((size_t)(b * 256 + o) * 32 + krow) * 16 + y) * 2 + hi] = val;
        }
    }
}

// 256-thread irfft2 + gelu(x1 + conv); sums 2 partials; twiddles hoisted.
__global__ void __launch_bounds__(256) k_irfft_fuse(const float* __restrict__ part,
        const ushort* __restrict__ x2t, ushort* __restrict__ tmp) {
    __shared__ float F[32][16][2];
    __shared__ alignas(16) float tre[16][68], tim[16][68];
    __shared__ float twc[64], tws[64];
    int p = blockIdx.x;
    int t = threadIdx.x;
    int h = t & 63, grp = t >> 6;
    const float2* s0 = (const float2*)part + (size_t)p * 512;
    #pragma unroll
    for (int l = 0; l < 2; ++l) {
        int idx = t + l * 256;
        float2 a = s0[idx];
        float2 b2 = s0[idx + 2097152];
        ((float2*)F)[idx] = make_float2(a.x + b2.x, a.y + b2.y);
    }
    if (t < 64) {
        twc[t] = cosf((float)t * (6.283185307179586f / 64.0f));
        tws[t] = sinf((float)t * (6.283185307179586f / 64.0f));
    }
    __syncthreads();
    {
        float reA[4], imA[4];
        #pragma unroll
        for (int q = 0; q < 4; ++q) { reA[q] = 0.f; imA[q] = 0.f; }
        #pragma unroll
        for (int krow = 0; krow < 32; ++krow) {
            int kh = krow < 16 ? krow : krow + 32;
            int j = (h * kh) & 63;
            float c = twc[j], s = tws[j];
            #pragma unroll
            for (int q = 0; q < 4; ++q) {
                int kw = grp + q * 4;
                float fr = F[krow][kw][0], fi = F[krow][kw][1];
                reA[q] += fr * c - fi * s;
                imA[q] += fr * s + fi * c;
            }
        }
        #pragma unroll
        for (int q = 0; q < 4; ++q) {
            int kw = grp + q * 4;
            tre[kw][h] = reA[q] * (1.f / 64.f);
            tim[kw][h] = imA[q] * (1.f / 64.f);
        }
    }
    __syncthreads();
    int w = h;
    float twcr[15], twsr[15];
    #pragma unroll
    for (int kw = 1; kw < 16; ++kw) {
        int j = (w * kw) & 63;
        twcr[kw - 1] = 2.f * twc[j];
        twsr[kw - 1] = 2.f * tws[j];
    }
    float accv[16];
    #pragma unroll
    for (int v4 = 0; v4 < 4; ++v4) {
        float4 tr = *(const float4*)&tre[0][grp * 16 + v4 * 4];
        accv[v4 * 4 + 0] = tr.x; accv[v4 * 4 + 1] = tr.y;
        accv[v4 * 4 + 2] = tr.z; accv[v4 * 4 + 3] = tr.w;
    }
    #pragma unroll
    for (int kw = 1; kw < 16; ++kw) {
        float c = twcr[kw - 1], s = twsr[kw - 1];
        #pragma unroll
        for (int v4 = 0; v4 < 4; ++v4) {
            float4 tr = *(const float4*)&tre[kw][grp * 16 + v4 * 4];
            float4 ti = *(const float4*)&tim[kw][grp * 16 + v4 * 4];
            accv[v4 * 4 + 0] += tr.x * c - ti.x * s;
            accv[v4 * 4 + 1] += tr.y * c - ti.y * s;
            accv[v4 * 4 + 2] += tr.z * c - ti.z * s;
            accv[v4 * 4 + 3] += tr.w * c - ti.w * s;
        }
    }
    const ushort* x2p = x2t + (size_t)p * 4096;
    ushort* tp = tmp + (size_t)p * 4096;
    #pragma unroll
    for (int qq = 0; qq < 16; ++qq) {
        int qrow = grp * 16 + qq;
        float x1 = accv[qq] * (1.f / 64.f);
        int idx = qrow * 64 + w;
        tp[idx] = f2bf(gelu_f(x1 + b2f(x2p[idx])));
    }
}

// transpose tmp(bf16) [b][d][n] -> e0t bf16 [b][n][d] (no residual/cw)
__global__ void k_fno_final(const ushort* __restrict__ tmp, ushort* __restrict__ e0t) {
    __shared__ ushort tile[32][34];
    int b = blockIdx.z;
    int n0 = blockIdx.x * 32, d0 = blockIdx.y * 32;
    int tx = threadIdx.x, ty = threadIdx.y;
    const ushort* tb = tmp + (size_t)b * DD * NN;
    #pragma unroll
    for (int i = 0; i < 4; ++i)
        tile[ty + i * 8][tx] = tb[(size_t)(d0 + ty + i * 8) * NN + n0 + tx];
    __syncthreads();
    #pragma unroll
    for (int i = 0; i < 4; ++i) {
        int n = n0 + ty + i * 8, d = d0 + tx;
        e0t[((size_t)b * NN + n) * DD + d] = tile[tx][ty + i * 8];
    }
}

// ---------------- layernorm (bf16 in, bf16 out) ----------------
__global__ void __launch_bounds__(256) k_ln(const ushort* __restrict__ in, const float* __restrict__ g,
        const float* __restrict__ be, ushort* __restrict__ outb) {
    int row = blockIdx.x * 4 + (threadIdx.x >> 6);
    int lane = threadIdx.x & 63;
    ushort4 u = ((const ushort4*)(in + (size_t)row * 256))[lane];
    float4 v = make_float4(b2f(u.x), b2f(u.y), b2f(u.z), b2f(u.w));
    float s = v.x + v.y + v.z + v.w;
    float s2 = v.x * v.x + v.y * v.y + v.z * v.z + v.w * v.w;
    #pragma unroll
    for (int off = 32; off > 0; off >>= 1) {
        s += __shfl_down(s, off);
        s2 += __shfl_down(s2, off);
    }
    s = __shfl(s, 0); s2 = __shfl(s2, 0);
    float mu = s * (1.f / 256.f);
    float var = s2 * (1.f / 256.f) - mu * mu;
    float rstd = rsqrtf(var + 1e-5f);
    float4 gv = ((const float4*)g)[lane];
    float4 bv = ((const float4*)be)[lane];
    ushort4 ov;
    ov.x = f2bf((v.x - mu) * rstd * gv.x + bv.x);
    ov.y = f2bf((v.y - mu) * rstd * gv.y + bv.y);
    ov.z = f2bf((v.z - mu) * rstd * gv.z + bv.z);
    ov.w = f2bf((v.w - mu) * rstd * gv.w + bv.w);
    ((ushort4*)(outb + (size_t)row * 256))[lane] = ov;
}

// ---------------- MFMA window attention ----------------
__global__ void __launch_bounds__(256) k_window_attn(const ushort* __restrict__ qkvb,
        ushort* __restrict__ aob) {
    __shared__ ushort lds[4 * 7424];
    int t = threadIdx.x;
    int w = t >> 6, lane = t & 63;
    int wi = blockIdx.x, hh = blockIdx.y;
    int hd = hh * 4 + w;
    int b = wi >> 6, hb = (wi >> 3) & 7, wb = wi & 7;
    ushort* A = lds + w * 7424;
    ushort* Kl = A + 2560;
    ushort* Vt = A + 5120;
    int rlo = lane & 15, kq = lane >> 4;

    int tok = lane;
    int n = hb * 512 + wb * 8 + ((tok >> 3) << 6) + (tok & 7);
    const ushort* gq = qkvb + ((size_t)b * 4096 + n) * 768 + hd * 32;
    const uint4* qp = (const uint4*)gq;
    const uint4* kp = (const uint4*)(gq + 256);
    const uint4* vp = (const uint4*)(gq + 512);
    uint4 q0 = qp[0], q1 = qp[1], q2 = qp[2], q3 = qp[3];
    uint4 k0 = kp[0], k1 = kp[1], k2 = kp[2], k3 = kp[3];
    uint4 v0 = vp[0], v1 = vp[1], v2 = vp[2], v3 = vp[3];
    uint4* qr = (uint4*)(A + tok * 40);
    qr[0] = q0; qr[1] = q1; qr[2] = q2; qr[3] = q3;
    uint4* kr = (uint4*)(Kl + tok * 40);
    kr[0] = k0; kr[1] = k1; kr[2] = k2; kr[3] = k3;
    ushort vbuf[32];
    *(uint4*)&vbuf[0] = v0; *(uint4*)&vbuf[8] = v1;
    *(uint4*)&vbuf[16] = v2; *(uint4*)&vbuf[24] = v3;
    #pragma unroll
    for (int d = 0; d < 32; ++d) Vt[d * 72 + tok] = vbuf[d];
    __syncthreads();

    bf16x8 Qf[4], Kf[4];
    #pragma unroll
    for (int lt = 0; lt < 4; ++lt)
        Qf[lt] = *(const bf16x8*)(A + (lt * 16 + rlo) * 40 + kq * 8);
    #pragma unroll
    for (int mt = 0; mt < 4; ++mt)
        Kf[mt] = *(const bf16x8*)(Kl + (mt * 16 + rlo) * 40 + kq * 8);

    f32x4 S[4][4];
    #pragma unroll
    for (int lt = 0; lt < 4; ++lt)
        #pragma unroll
        for (int mt = 0; mt < 4; ++mt)
            S[lt][mt] = __builtin_amdgcn_mfma_f32_16x16x32_bf16(Qf[lt], Kf[mt],
                        (f32x4){0.f, 0.f, 0.f, 0.f}, 0, 0, 0);
    __syncthreads();

    const float scale = 0.17677669529663687f;
    float inv_[4][4];
    #pragma unroll
    for (int lt = 0; lt < 4; ++lt) {
        float m4[4], s4[4];
        #pragma unroll
        for (int j = 0; j < 4; ++j) {
            m4[j] = fmaxf(fmaxf(S[lt][0][j], S[lt][1][j]), fmaxf(S[lt][2][j], S[lt][3][j]));
        }
        #pragma unroll
        for (int off = 1; off < 16; off <<= 1)
            #pragma unroll
            for (int j = 0; j < 4; ++j) m4[j] = fmaxf(m4[j], __shfl_xor(m4[j], off));
        #pragma unroll
        for (int j = 0; j < 4; ++j) s4[j] = 0.f;
        #pragma unroll
        for (int mt = 0; mt < 4; ++mt)
            #pragma unroll
            for (int j = 0; j < 4; ++j) {
                float p = __expf((S[lt][mt][j] - m4[j]) * scale);
                s4[j] += p;
                A[(lt * 16 + kq * 4 + j) * 72 + mt * 16 + rlo] = f2bf(p);
            }
        #pragma unroll
        for (int off = 1; off < 16; off <<= 1)
            #pragma unroll
            for (int j = 0; j < 4; ++j) s4[j] += __shfl_xor(s4[j], off);
        #pragma unroll
        for (int j = 0; j < 4; ++j) inv_[lt][j] = 1.0f / s4[j];
    }
    __syncthreads();

    f32x4 O[4][2];
    #pragma unroll
    for (int lt = 0; lt < 4; ++lt)
        #pragma unroll
        for (int dt = 0; dt < 2; ++dt) {
            f32x4 o = (f32x4){0.f, 0.f, 0.f, 0.f};
            #pragma unroll
            for (int mc = 0; mc < 2; ++mc) {
                bf16x8 pa = *(const bf16x8*)(A + (lt * 16 + rlo) * 72 + mc * 32 + kq * 8);
                bf16x8 vb = *(const bf16x8*)(Vt + (dt * 16 + rlo) * 72 + mc * 32 + kq * 8);
                o = __builtin_amdgcn_mfma_f32_16x16x32_bf16(pa, vb, o, 0, 0, 0);
            }
            O[lt][dt] = o;
        }
    __syncthreads();

    #pragma unroll
    for (int lt = 0; lt < 4; ++lt)
        #pragma unroll
        for (int dt = 0; dt < 2; ++dt)
            #pragma unroll
            for (int j = 0; j < 4; ++j)
                A[(lt * 16 + kq * 4 + j) * 40 + dt * 16 + rlo] = f2bf(O[lt][dt][j] * inv_[lt][j]);
    __syncthreads();
    const uint4* orow = (const uint4*)(A + lane * 40);
    uint4 o0 = orow[0], o1 = orow[1], o2 = orow[2], o3 = orow[3];
    uint4* gout = (uint4*)(aob + ((size_t)b * 4096 + n) * 256 + hd * 32);
    gout[0] = o0; gout[1] = o1; gout[2] = o2; gout[3] = o3;
}

extern "C" void kernel_launch(void* const* d_in, const int* in_sizes, int n_in,
                              void* d_out, int out_size, void* d_ws, size_t ws_size,
                              hipStream_t stream) {
    (void)in_sizes; (void)n_in; (void)out_size; (void)ws_size;
    const float* x        = (const float*)d_in[0];
    const float* text     = (const float*)d_in[1];
    const float* gate_w1  = (const float*)d_in[2];
    const float* gate_b1  = (const float*)d_in[3];
    const float* gate_w2  = (const float*)d_in[4];
    const float* gate_b2  = (const float*)d_in[5];
    const float* fno_w1r  = (const float*)d_in[6];
    const float* fno_w1i  = (const float*)d_in[7];
    const float* fno_w2r  = (const float*)d_in[8];
    const float* fno_w2i  = (const float*)d_in[9];
    const float* fno_cw   = (const float*)d_in[10];
    const float* fno_cb   = (const float*)d_in[11];
    const float* mlp1_w1  = (const float*)d_in[12];
    const float* mlp1_b1  = (const float*)d_in[13];
    const float* mlp1_w2  = (const float*)d_in[14];
    const float* mlp1_b2  = (const float*)d_in[15];
    const float* mlp2_w1  = (const float*)d_in[16];
    const float* mlp2_b1  = (const float*)d_in[17];
    const float* mlp2_w2  = (const float*)d_in[18];
    const float* mlp2_b2  = (const float*)d_in[19];
    const float* ln1_g    = (const float*)d_in[20];
    const float* ln1_b    = (const float*)d_in[21];
    const float* qkv_w    = (const float*)d_in[22];
    const float* qkv_b    = (const float*)d_in[23];
    const float* out_w    = (const float*)d_in[24];
    const float* out_b    = (const float*)d_in[25];
    const float* ln2_g    = (const float*)d_in[26];
    const float* ln2_b    = (const float*)d_in[27];
    const float* wa_w1    = (const float*)d_in[28];
    const float* wa_b1    = (const float*)d_in[29];
    const float* wa_w2    = (const float*)d_in[30];
    const float* wa_b2    = (const float*)d_in[31];

    float* ws   = (float*)d_ws;
    float* h1   = ws + 8192;         // 2048
    float* cwp  = ws + 10240;        // 32
    ushort* wbf = (ushort*)(ws + 16384);     // weight bf16 pool
    ushort* w1aT = wbf;
    ushort* w2aT = w1aT + 262144;
    ushort* w1bT = w2aT + 262144;
    ushort* w2bT = w1bT + 262144;
    ushort* w1cT = w2bT + 262144;
    ushort* w2cT = w1cT + 262144;
    ushort* qkvT = w2cT + 262144;
    ushort* outwT = qkvT + 196608;
    ushort* convT = outwT + 65536;
    ushort* Xbf  = (ushort*)(ws + 16384 + 1048576);          // bf16 x
    float* slotA = ws + 16384 + 1048576 + 4194304;           // 8.39M floats
    float* xft   = slotA + 8388608;                          // 2.1M
    float* oft   = xft + 2097152;                            // 2.1M
    float* regD  = oft + 2097152;                            // 8.39M
    ushort* bigb = (ushort*)(regD + 8388608);                // tmp/qkv/hidden bf16
    float* gpart = oft;     // 262144 floats (gating phase only)

    // timeline-reused bf16 buffers
    ushort* xgb   = (ushort*)slotA;                // xg bf16 (FNO)
    ushort* g1b   = (ushort*)slotA;                // expert1 gemm2 out (after FNO)
    ushort* g2b   = (ushort*)(slotA + 4194304);    // expert2 gemm2 out
    ushort* x2tb  = (ushort*)regD;                 // conv branch bf16
    ushort* e0tb  = (ushort*)regD;                 // fno transposed out (after irfft)
    ushort* scr   = (ushort*)(regD + 4194304);     // ln-out / attn_o / ln2-out
    ushort* xatb  = (ushort*)xft;                  // xattn bf16 (xft+oft region, after spectral)

    float* outp = (float*)d_out;
    float* wout = outp + (size_t)NB * NN * DD;

    // fused conversion + transpose + gate-mean partials, then gating
    k_cvt_gate_t<<<dim3(128, 8, 8), dim3(32, 8), 0, stream>>>(x, Xbf, xgb, gpart);
    k_gate_mm<<<dim3(8, 8), 256, 0, stream>>>(gpart, text, gate_w1, gate_b1, h1);
    k_gate_top<<<1, 64, 0, stream>>>(h1, gate_w2, gate_b2, cwp, wout);

    // prep: all weight bf16 conversions in one launch
    k_wt_all<<<dim3(256, 1, 9), dim3(32, 8), 0, stream>>>(
        mlp1_w1, mlp1_w2, mlp2_w1, mlp2_w2, wa_w1, wa_w2, qkv_w, out_w, fno_cw,
        w1aT, w2aT, w1bT, w2bT, w1cT, w2cT, qkvT, outwT, convT);

    // expert 0: FNO -> e0tb (pure gelu-term, bf16, row-major)
    k_rfft2<<<2048, 256, 0, stream>>>(xgb, xft);
    k_gemm<5><<<dim3(2, 32, 8), 256, 0, stream>>>(convT, Xbf, fno_cb, nullptr, nullptr,
        x2tb, nullptr, 0, 256, 4096, 0, (size_t)NN * DD, (size_t)DD * NN,
        nullptr, nullptr, nullptr, nullptr);
    k_spectral<<<dim3(16, 16, 4), 512, 0, stream>>>(xft, fno_w1r, fno_w1i, fno_w2r, fno_w2i, slotA);
    k_irfft_fuse<<<2048, 256, 0, stream>>>(slotA, x2tb, bigb);
    k_fno_final<<<dim3(128, 8, 8), dim3(32, 8), 0, stream>>>(bigb, e0tb);

    // expert 1: MLP -> g1b
    k_gemm<0><<<dim3(256, 8), 256, 0, stream>>>(Xbf, w1aT, mlp1_b1, nullptr, nullptr, bigb, nullptr, 0, 256, 1024, 0, 0, 0, nullptr, nullptr, nullptr, nullptr);
    k_gemm<1><<<dim3(256, 2), 256, 0, stream>>>(bigb, w2aT, mlp1_b2, nullptr, nullptr, g1b, nullptr, 0, 1024, 256, 0, 0, 0, nullptr, nullptr, nullptr, nullptr);

    // expert 2: window attention -> xatb (residual stream) and g2b (mlp out)
    k_ln<<<8192, 256, 0, stream>>>(Xbf, ln1_g, ln1_b, scr);
    k_gemm<1><<<dim3(256, 6), 256, 0, stream>>>(scr, qkvT, qkv_b, nullptr, nullptr, bigb, nullptr, 0, 256, 768, 0, 0, 0, nullptr, nullptr, nullptr, nullptr);
    k_window_attn<<<dim3(512, 2), 256, 0, stream>>>(bigb, scr);
    k_gemm<6><<<dim3(256, 2), 256, 0, stream>>>(scr, outwT, out_b, Xbf, nullptr, xatb, nullptr, 0, 256, 256, 0, 0, 0, nullptr, nullptr, nullptr, nullptr);
    k_ln<<<8192, 256, 0, stream>>>(xatb, ln2_g, ln2_b, scr);
    k_gemm<0><<<dim3(256, 8), 256, 0, stream>>>(scr, w1cT, wa_b1, nullptr, nullptr, bigb, nullptr, 0, 256, 1024, 0, 0, 0, nullptr, nullptr, nullptr, nullptr);
    k_gemm<1><<<dim3(256, 2), 256, 0, stream>>>(bigb, w2cT, wa_b2, nullptr, nullptr, g2b, nullptr, 0, 1024, 256, 0, 0, 0, nullptr, nullptr, nullptr, nullptr);

    // expert 3: MLP, gemm2 fuses the final combine and writes out directly
    k_gemm<0><<<dim3(256, 8), 256, 0, stream>>>(Xbf, w1bT, mlp2_b1, nullptr, nullptr, bigb, nullptr, 0, 256, 1024, 0, 0, 0, nullptr, nullptr, nullptr, nullptr);
    k_gemm<7><<<dim3(256, 2), 256, 0, stream>>>(bigb, w2bT, mlp2_b2, Xbf, outp, nullptr, cwp, 3, 1024, 256, 0, 0, 0, e0tb, g1b, g2b, xatb);
}